// Round 8
// baseline (116.442 us; speedup 1.0000x reference)
//
#include <hip/hip_runtime.h>
#include <hip/hip_bf16.h>

// SimpleRetention: B=8, SEQ=2048, HIDDEN=512, HEAD=64, CHUNK=256, GAMMA=0.96875
// v8: v7 +
//   prep: native-HW transcendentals (exp2f/__log2f/__sinf/__cosf, no libm powf)
//   proj: A-frags loaded directly from global X (no X LDS staging, 1 barrier)

typedef __attribute__((ext_vector_type(8))) short short8;
typedef __attribute__((ext_vector_type(4))) float floatx4;

#define LOG2GAMMA (-0.04580350f)   // log2(0.96875)
#define GINV      (1.0f / 0.96875f)
#define LOG2_10K  (13.287712379549449f)  // log2(10000)

static __device__ __forceinline__ unsigned short f2bf(float f) {
    __hip_bfloat16 h = __float2bfloat16(f);
    return *reinterpret_cast<unsigned short*>(&h);
}

// Fragment storage convention (per 16x16x32 MFMA operand, 16 B per lane):
//   slot = (frag_index*64 + lane)*8, lane = quad*16 + l15
//   A-frag: l15 = row m, k = quad*8+j   |   B-frag: l15 = col n, k = quad*8+j

// ---------------------------------------------------------------------------
// Kernel 0: Wfrag (B-frag order, tiles 0..3=WQ 4..7=WK 8..11=WV) + xpos tables
// tabs: 4 tables of [2048][32] f32: 0=cosQ 1=sinQ 2=cosK 3=sinK
// ---------------------------------------------------------------------------
__global__ __launch_bounds__(256) void prep_kernel(
    const float* __restrict__ Wq, const float* __restrict__ Wk,
    const float* __restrict__ Wv,
    __hip_bfloat16* __restrict__ Wfrag, float* __restrict__ tabs)
{
    int idx = blockIdx.x * 256 + threadIdx.x;
    const int WF_N = 192 * 512;
    if (idx < WF_N) {
        int j    = idx & 7;
        int n15  = (idx >> 3) & 15;
        int quad = (idx >> 7) & 3;
        int kkg  = (idx >> 9) & 15;
        int tile = idx >> 13;              // 0..11
        int n = tile * 16 + n15;           // 0..191 (proj output channel)
        int k = kkg * 32 + quad * 8 + j;   // 0..511 (hidden)
        int m = n >> 6, c = n & 63;
        const float* W = (m == 0) ? Wq : ((m == 1) ? Wk : Wv);
        Wfrag[idx] = __float2bfloat16(W[k * 64 + c]);
    } else {
        int t2 = idx - WF_N;
        if (t2 < 4 * 2048 * 32) {
            int tab = t2 >> 16;          // 0..3
            int rem = t2 & 65535;
            int pos = rem >> 5;          // 0..2047
            int t   = rem & 31;          // 0..31
            // native-HW transcendentals (v_exp/v_log/v_sin/v_cos)
            float inv_freq = exp2f((float)t * (-LOG2_10K / 32.0f));
            float sinus = (float)pos * inv_freq;
            float s = __sinf(sinus), c = __cosf(sinus);
            float sv = (2.0f * (float)t + 25.6f) / 89.6f;      // in [0.286, 0.978]
            float power = (float)pos * (1.0f / 512.0f);
            float e = ((tab >= 2) ? -power : power) * __log2f(sv);
            float scl = exp2f(e);
            tabs[t2] = ((tab & 1) == 0) ? c * scl : s * scl;
        }
    }
}

// ---------------------------------------------------------------------------
// Kernel 1: projections + fragment materialization.
// 512 blocks x 32 rows, 4 waves. Wave nh: tiles 3nh..3nh+2 x all 32 rows.
// A-frags loaded DIRECTLY from global X (rows are k-contiguous: 2 float4 per
// lane per k-step, 128-B segments, L1-broadcast across the 4 waves). No X
// LDS staging; LDS (14 KB) only for the epilogue transpose. One barrier.
// Epilogue: Qfrag (A-layout), Kfrag (B), Vfrag (B), Ktfrag (A-layout K^T
// scaled by gamma^(255-jl) for the Z GEMM).
// ---------------------------------------------------------------------------
__global__ __launch_bounds__(256, 4) void proj_kernel(
    const float* __restrict__ X, const __hip_bfloat16* __restrict__ Wfrag,
    const float* __restrict__ tabs,
    __hip_bfloat16* __restrict__ Qfrag, __hip_bfloat16* __restrict__ Kfrag,
    __hip_bfloat16* __restrict__ Vfrag, __hip_bfloat16* __restrict__ Ktfrag)
{
    __shared__ __hip_bfloat16 smem[7168];   // 14336 B
    // bufQ=+0 [32][72], bufK=+2304 [32][72], bufV=+4608 [64][40] (transposed)

    int tid = threadIdx.x;
    int r0 = blockIdx.x * 32;               // global row base (b*2048 + n)
    int nh = tid >> 6, lane = tid & 63, quad = lane >> 4, l15 = lane & 15;

    const float* xp0 = X + (size_t)(r0 + l15) * 512 + quad * 8;       // row l15
    const float* xp1 = xp0 + 16 * 512;                                 // row 16+l15

    // acc[tl*2 + r]: tile 3nh+tl, row-half r
    floatx4 acc[6];
#pragma unroll
    for (int t = 0; t < 6; t++) acc[t] = (floatx4){0.f, 0.f, 0.f, 0.f};

#pragma unroll
    for (int ks = 0; ks < 16; ks++) {
        float4 x00 = *(const float4*)(xp0 + ks * 32);
        float4 x01 = *(const float4*)(xp0 + ks * 32 + 4);
        float4 x10 = *(const float4*)(xp1 + ks * 32);
        float4 x11 = *(const float4*)(xp1 + ks * 32 + 4);
        short8 a0, a1;
        a0[0] = (short)f2bf(x00.x); a0[1] = (short)f2bf(x00.y);
        a0[2] = (short)f2bf(x00.z); a0[3] = (short)f2bf(x00.w);
        a0[4] = (short)f2bf(x01.x); a0[5] = (short)f2bf(x01.y);
        a0[6] = (short)f2bf(x01.z); a0[7] = (short)f2bf(x01.w);
        a1[0] = (short)f2bf(x10.x); a1[1] = (short)f2bf(x10.y);
        a1[2] = (short)f2bf(x10.z); a1[3] = (short)f2bf(x10.w);
        a1[4] = (short)f2bf(x11.x); a1[5] = (short)f2bf(x11.y);
        a1[6] = (short)f2bf(x11.z); a1[7] = (short)f2bf(x11.w);
#pragma unroll
        for (int tl = 0; tl < 3; tl++) {
            int tile = nh * 3 + tl;
            short8 bfr = *(const short8*)(Wfrag + ((tile * 16 + ks) * 64 + lane) * 8);
            acc[tl * 2 + 0] = __builtin_amdgcn_mfma_f32_16x16x32_bf16(a0, bfr, acc[tl * 2 + 0], 0, 0, 0);
            acc[tl * 2 + 1] = __builtin_amdgcn_mfma_f32_16x16x32_bf16(a1, bfr, acc[tl * 2 + 1], 0, 0, 0);
        }
    }

    // ---- epilogue. C/D layout: col = l15, row = quad*4+rg (+16*r) ----
    __hip_bfloat16* bufQ = smem;
    __hip_bfloat16* bufK = smem + 2304;
    __hip_bfloat16* bufV = smem + 4608;
    int b = r0 >> 11, n0 = r0 & 2047;

#pragma unroll
    for (int tl = 0; tl < 3; tl++) {
        int t = nh * 3 + tl;
#pragma unroll
        for (int r = 0; r < 2; r++) {
#pragma unroll
            for (int rg = 0; rg < 4; rg++) {
                int row = r * 16 + quad * 4 + rg;    // 0..31 within block
                int n = n0 + row;
                float val = acc[tl * 2 + r][rg];
                float prt = __shfl_xor(val, 1, 64);  // lane^1 == col^1, same row
                if (t < 4) {                    // Q, xpos upscale
                    int ch = t * 16 + l15, tt = ch >> 1;
                    float co = tabs[n * 32 + tt];
                    float si = tabs[65536 + n * 32 + tt];
                    float o = (l15 & 1) ? (val * co + prt * si) : (val * co - prt * si);
                    bufQ[row * 72 + ch] = __float2bfloat16(o);
                } else if (t < 8) {             // K, xpos downscale
                    int ch = (t - 4) * 16 + l15, tt = ch >> 1;
                    float co = tabs[131072 + n * 32 + tt];
                    float si = tabs[196608 + n * 32 + tt];
                    float o = (l15 & 1) ? (val * co + prt * si) : (val * co - prt * si);
                    bufK[row * 72 + ch] = __float2bfloat16(o);
                } else {                        // V, transposed [ch][row]
                    int ch = (t - 8) * 16 + l15;
                    bufV[ch * 40 + row] = __float2bfloat16(val);
                }
            }
        }
    }
    __syncthreads();

    // ---- cooperative frag-order stores ----
    {
        int tile2 = tid >> 7, kk = (tid >> 6) & 1, ln = tid & 63;
        int q2 = ln >> 4, m15 = ln & 15;
        size_t qkbase = ((((size_t)b * 128 + (n0 >> 4) + tile2) * 2 + kk) * 64 + ln) * 8;
        uint4 vq = *(const uint4*)&bufQ[(tile2 * 16 + m15) * 72 + kk * 32 + q2 * 8];
        *(uint4*)(Qfrag + qkbase) = vq;
        uint4 vk = *(const uint4*)&bufK[(tile2 * 16 + m15) * 72 + kk * 32 + q2 * 8];
        *(uint4*)(Kfrag + qkbase) = vk;
        int t2 = tid >> 6;                  // 0..3
        uint4 vv = *(const uint4*)&bufV[(t2 * 16 + m15) * 40 + q2 * 8];
        *(uint4*)(Vfrag + ((((size_t)b * 64 + (n0 >> 5)) * 4 + t2) * 64 + ln) * 8) = vv;
    }
    // ---- Ktfrag: A-layout of K^T scaled by gamma^(255-jl), for Z = Ks^T V ----
    {
        int wdt = tid >> 6, ln2 = tid & 63;          // wdt = d-tile 0..3
        int q2 = ln2 >> 4, m15 = ln2 & 15;           // m15 = d within tile
        int jb0 = (n0 & 255) + q2 * 8;               // base key (chunk-local)
        float sc = exp2f(LOG2GAMMA * (float)(255 - jb0));
        short8 pk;
#pragma unroll
        for (int jj = 0; jj < 8; jj++) {
            float v = __bfloat162float(bufK[(q2 * 8 + jj) * 72 + wdt * 16 + m15]) * sc;
            pk[jj] = (short)f2bf(v);
            sc *= GINV;
        }
        int c = n0 >> 8, ksg = (n0 >> 5) & 7;
        *(short8*)(Ktfrag + ((((size_t)(b * 8 + c) * 4 + wdt) * 8 + ksg) * 64 + ln2) * 8) = pk;
    }
}

// ---------------------------------------------------------------------------
// Kernel 2: partial Z: Z[b][c][kh] = sum over keys kh*128..+127 of Ks^T V.
// 128 blocks = (b, c, kh), 4 waves (wave = d-tile). Output in B-frag order
// (f32) via LDS transpose; attn sums the two kh partials.
// ---------------------------------------------------------------------------
__global__ __launch_bounds__(256, 2) void zk_kernel(
    const __hip_bfloat16* __restrict__ Ktfrag,
    const __hip_bfloat16* __restrict__ Vfrag, float* __restrict__ Zf)
{
    __shared__ float zz[64 * 68];   // 17408 B

    int tid = threadIdx.x;
    int b = blockIdx.x >> 4, c = (blockIdx.x >> 1) & 7, kh = blockIdx.x & 1;
    int w = tid >> 6, lane = tid & 63, quad = lane >> 4, l15 = lane & 15;

    floatx4 acc[4];
#pragma unroll
    for (int t = 0; t < 4; t++) acc[t] = (floatx4){0.f, 0.f, 0.f, 0.f};

#pragma unroll
    for (int ks = 0; ks < 4; ks++) {
        int ksg = kh * 4 + ks;
        short8 a = *(const short8*)(Ktfrag +
            ((((size_t)(b * 8 + c) * 4 + w) * 8 + ksg) * 64 + lane) * 8);
#pragma unroll
        for (int vt = 0; vt < 4; vt++) {
            short8 bfr = *(const short8*)(Vfrag +
                ((((size_t)b * 64 + c * 8 + ksg) * 4 + vt) * 64 + lane) * 8);
            acc[vt] = __builtin_amdgcn_mfma_f32_16x16x32_bf16(a, bfr, acc[vt], 0, 0, 0);
        }
    }
    // C-layout (row d = w*16+quad*4+rg, col v = vt*16+l15) -> LDS
#pragma unroll
    for (int vt = 0; vt < 4; vt++)
#pragma unroll
        for (int rg = 0; rg < 4; rg++)
            zz[(w * 16 + quad * 4 + rg) * 68 + vt * 16 + l15] = acc[vt][rg];
    __syncthreads();

    // B-frag-order f32 store: thread = (vt, lane); 2 kk x 8 jd values
    {
        int vt = tid >> 6;
#pragma unroll
        for (int kk = 0; kk < 2; kk++) {
            float v[8];
#pragma unroll
            for (int jd = 0; jd < 8; jd++)
                v[jd] = zz[(kk * 32 + quad * 8 + jd) * 68 + vt * 16 + l15];
            float* zp = Zf +
                ((((((size_t)(b * 8 + c) * 2 + kh) * 4 + vt) * 2 + kk) * 64 + lane) * 8);
            *(float4*)zp       = (float4){v[0], v[1], v[2], v[3]};
            *(float4*)(zp + 4) = (float4){v[4], v[5], v[6], v[7]};
        }
    }
}

// ---------------------------------------------------------------------------
// Kernel 3: per-q-tile retention. 1024 blocks = (b, 128 q-tiles), 128 thr
// (2 waves). Wave h: diagonal-chunk keys h*128..+127 (QK + |i-j| decay + P
// round-trip + PV) and the kk=h half of the cross term Q @ H with post-MFMA
// row scaling by gamma^(il+1); H = sum_m g^(256m) * (Z[qc-1-m][0]+Z[..][1]).
// One barrier total.
// ---------------------------------------------------------------------------
__global__ __launch_bounds__(128, 4) void attn_kernel(
    const __hip_bfloat16* __restrict__ Qfrag, const __hip_bfloat16* __restrict__ Kfrag,
    const __hip_bfloat16* __restrict__ Vfrag, const float* __restrict__ Zf,
    float* __restrict__ out)
{
    __shared__ __hip_bfloat16 P[2 * 16 * 132];   // 8448 B (stride 132)
    __shared__ float obuf[16 * 68];              // 4352 B

    int tid = threadIdx.x;
    int b = blockIdx.x >> 7, qt = blockIdx.x & 127;
    int qc = qt >> 4;
    int h = tid >> 6, lane = tid & 63, quad = lane >> 4, l15 = lane & 15;
    __hip_bfloat16* Pw = P + h * 2112;

    short8 qf[2];
#pragma unroll
    for (int kk = 0; kk < 2; kk++)
        qf[kk] = *(const short8*)(Qfrag + (((size_t)(b * 128 + qt) * 2 + kk) * 64 + lane) * 8);

    floatx4 o[4];
#pragma unroll
    for (int t = 0; t < 4; t++) o[t] = (floatx4){0.f, 0.f, 0.f, 0.f};

    int il0 = (qt & 15) * 16 + quad * 4;         // chunk-local q row base

    // ---- diagonal chunk, this wave's 128 keys, 2 groups of 4 ktiles ----
#pragma unroll
    for (int g = 0; g < 2; g++) {
        floatx4 s[4];
#pragma unroll
        for (int t = 0; t < 4; t++) s[t] = (floatx4){0.f, 0.f, 0.f, 0.f};
#pragma unroll
        for (int t = 0; t < 4; t++) {
            int kt = qc * 16 + h * 8 + g * 4 + t;
#pragma unroll
            for (int kk = 0; kk < 2; kk++) {
                short8 bfr = *(const short8*)(Kfrag +
                    (((size_t)(b * 128 + kt) * 2 + kk) * 64 + lane) * 8);
                s[t] = __builtin_amdgcn_mfma_f32_16x16x32_bf16(qf[kk], bfr, s[t], 0, 0, 0);
            }
        }
#pragma unroll
        for (int t = 0; t < 4; t++) {
            int jl = h * 128 + (g * 4 + t) * 16 + l15;
#pragma unroll
            for (int rg = 0; rg < 4; rg++) {
                int d = il0 + rg - jl; d = (d < 0) ? -d : d;
                float p = s[t][rg] * exp2f(LOG2GAMMA * (float)d);
                Pw[(quad * 4 + rg) * 132 + (g * 4 + t) * 16 + l15] = __float2bfloat16(p);
            }
        }
    }
    // PV over this wave's 128 keys (in-wave DS ordering, no barrier)
#pragma unroll
    for (int ks = 0; ks < 4; ks++) {
        short8 a = *(const short8*)&Pw[l15 * 132 + ks * 32 + quad * 8];
#pragma unroll
        for (int vt = 0; vt < 4; vt++) {
            short8 bfr = *(const short8*)(Vfrag +
                ((((size_t)b * 64 + qc * 8 + h * 4 + ks) * 4 + vt) * 64 + lane) * 8);
            o[vt] = __builtin_amdgcn_mfma_f32_16x16x32_bf16(a, bfr, o[vt], 0, 0, 0);
        }
    }

    // ---- cross-chunk term: Q @ H into oc, post-scale by gamma^(il+1) ----
    if (qc > 0) {
        floatx4 oc[4];
#pragma unroll
        for (int t = 0; t < 4; t++) oc[t] = (floatx4){0.f, 0.f, 0.f, 0.f};
        int nz = (qc < 3) ? qc : 3;
        float cm1 = exp2f(LOG2GAMMA * 256.0f);
        float cm2 = exp2f(LOG2GAMMA * 512.0f);
#pragma unroll
        for (int vt = 0; vt < 4; vt++) {
            float hv[8];
#pragma unroll
            for (int jd = 0; jd < 8; jd++) hv[jd] = 0.f;
            for (int m = 0; m < nz; m++) {
                float cm = (m == 0) ? 1.0f : ((m == 1) ? cm1 : cm2);
#pragma unroll
                for (int kh = 0; kh < 2; kh++) {
                    const float* zp = Zf +
                        ((((((size_t)(b * 8 + qc - 1 - m) * 2 + kh) * 4 + vt) * 2 + h) * 64 + lane) * 8);
                    float4 z0 = *(const float4*)zp;
                    float4 z1 = *(const float4*)(zp + 4);
                    hv[0] += cm * z0.x; hv[1] += cm * z0.y;
                    hv[2] += cm * z0.z; hv[3] += cm * z0.w;
                    hv[4] += cm * z1.x; hv[5] += cm * z1.y;
                    hv[6] += cm * z1.z; hv[7] += cm * z1.w;
                }
            }
            short8 hb;
#pragma unroll
            for (int jd = 0; jd < 8; jd++) hb[jd] = (short)f2bf(hv[jd]);
            oc[vt] = __builtin_amdgcn_mfma_f32_16x16x32_bf16(qf[h], hb, oc[vt], 0, 0, 0);
        }
        float rs[4];
#pragma unroll
        for (int rg = 0; rg < 4; rg++)
            rs[rg] = exp2f(LOG2GAMMA * (float)(il0 + rg + 1));
#pragma unroll
        for (int vt = 0; vt < 4; vt++)
#pragma unroll
            for (int rg = 0; rg < 4; rg++)
                o[vt][rg] += oc[vt][rg] * rs[rg];
    }

    // ---- combine the two waves ----
    if (h == 1) {
#pragma unroll
        for (int vt = 0; vt < 4; vt++)
#pragma unroll
            for (int rg = 0; rg < 4; rg++)
                obuf[(quad * 4 + rg) * 68 + vt * 16 + l15] = o[vt][rg];
    }
    __syncthreads();
    if (h == 0) {
        int rbase = b * 2048 + qt * 16 + quad * 4;
#pragma unroll
        for (int vt = 0; vt < 4; vt++)
#pragma unroll
            for (int rg = 0; rg < 4; rg++)
                out[(size_t)(rbase + rg) * 64 + vt * 16 + l15] =
                    o[vt][rg] + obuf[(quad * 4 + rg) * 68 + vt * 16 + l15];
    }
}

// ---------------------------------------------------------------------------
extern "C" void kernel_launch(void* const* d_in, const int* in_sizes, int n_in,
                              void* d_out, int out_size, void* d_ws, size_t ws_size,
                              hipStream_t stream) {
    const float* X  = (const float*)d_in[0];
    const float* Wq = (const float*)d_in[1];
    const float* Wk = (const float*)d_in[2];
    const float* Wv = (const float*)d_in[3];
    float* out = (float*)d_out;

    char* ws = (char*)d_ws;
    __hip_bfloat16* Wfrag  = (__hip_bfloat16*)(ws);             // 196608 B
    float*          tabs   = (float*)(ws + 196608);             // 1048576 B
    __hip_bfloat16* Qfrag  = (__hip_bfloat16*)(ws + 1245184);   // 2097152 B
    __hip_bfloat16* Kfrag  = (__hip_bfloat16*)(ws + 3342336);   // 2097152 B
    __hip_bfloat16* Vfrag  = (__hip_bfloat16*)(ws + 5439488);   // 2097152 B
    __hip_bfloat16* Ktfrag = (__hip_bfloat16*)(ws + 7536640);   // 2097152 B
    float*          Zf     = (float*)(ws + 9633792);            // 2097152 B

    prep_kernel<<<1408, 256, 0, stream>>>(Wq, Wk, Wv, Wfrag, tabs);
    proj_kernel<<<512, 256, 0, stream>>>(X, Wfrag, tabs, Qfrag, Kfrag, Vfrag, Ktfrag);
    zk_kernel<<<128, 256, 0, stream>>>(Ktfrag, Vfrag, Zf);
    attn_kernel<<<1024, 128, 0, stream>>>(Qfrag, Kfrag, Vfrag, Zf, out);
}

// Round 9
// 108.650 us; speedup vs baseline: 1.0717x; 1.0717x over previous
//
#include <hip/hip_runtime.h>
#include <hip/hip_bf16.h>

// SimpleRetention: B=8, SEQ=2048, HIDDEN=512, HEAD=64, CHUNK=256, GAMMA=0.96875
// v9 = v7 (best measured: 111.48 us) + prep native transcendentals only.
//   R8 lesson: direct-global A-frags regressed (strided 16B/lane gather +
//   per-k-step repack VALU); v7's stage-once LDS + ds_read_b128 is better.

typedef __attribute__((ext_vector_type(8))) short short8;
typedef __attribute__((ext_vector_type(4))) float floatx4;

#define LOG2GAMMA (-0.04580350f)   // log2(0.96875)
#define GINV      (1.0f / 0.96875f)
#define LOG2_10K  (13.287712379549449f)  // log2(10000)

static __device__ __forceinline__ unsigned short f2bf(float f) {
    __hip_bfloat16 h = __float2bfloat16(f);
    return *reinterpret_cast<unsigned short*>(&h);
}

// Fragment storage convention (per 16x16x32 MFMA operand, 16 B per lane):
//   slot = (frag_index*64 + lane)*8, lane = quad*16 + l15
//   A-frag: l15 = row m, k = quad*8+j   |   B-frag: l15 = col n, k = quad*8+j

// ---------------------------------------------------------------------------
// Kernel 0: Wfrag (B-frag order, tiles 0..3=WQ 4..7=WK 8..11=WV) + xpos tables
// tabs: 4 tables of [2048][32] f32: 0=cosQ 1=sinQ 2=cosK 3=sinK
// ---------------------------------------------------------------------------
__global__ __launch_bounds__(256) void prep_kernel(
    const float* __restrict__ Wq, const float* __restrict__ Wk,
    const float* __restrict__ Wv,
    __hip_bfloat16* __restrict__ Wfrag, float* __restrict__ tabs)
{
    int idx = blockIdx.x * 256 + threadIdx.x;
    const int WF_N = 192 * 512;
    if (idx < WF_N) {
        int j    = idx & 7;
        int n15  = (idx >> 3) & 15;
        int quad = (idx >> 7) & 3;
        int kkg  = (idx >> 9) & 15;
        int tile = idx >> 13;              // 0..11
        int n = tile * 16 + n15;           // 0..191 (proj output channel)
        int k = kkg * 32 + quad * 8 + j;   // 0..511 (hidden)
        int m = n >> 6, c = n & 63;
        const float* W = (m == 0) ? Wq : ((m == 1) ? Wk : Wv);
        Wfrag[idx] = __float2bfloat16(W[k * 64 + c]);
    } else {
        int t2 = idx - WF_N;
        if (t2 < 4 * 2048 * 32) {
            int tab = t2 >> 16;          // 0..3
            int rem = t2 & 65535;
            int pos = rem >> 5;          // 0..2047
            int t   = rem & 31;          // 0..31
            // native-HW transcendentals (v_exp/v_log/v_sin/v_cos)
            float inv_freq = exp2f((float)t * (-LOG2_10K / 32.0f));
            float sinus = (float)pos * inv_freq;
            float s = __sinf(sinus), c = __cosf(sinus);
            float sv = (2.0f * (float)t + 25.6f) / 89.6f;      // in [0.286, 0.978]
            float power = (float)pos * (1.0f / 512.0f);
            float e = ((tab >= 2) ? -power : power) * __log2f(sv);
            float scl = exp2f(e);
            tabs[t2] = ((tab & 1) == 0) ? c * scl : s * scl;
        }
    }
}

// ---------------------------------------------------------------------------
// Kernel 1: projections + fragment materialization (v7 version).
// 512 blocks x 32 rows, 4 waves. Wave nh: tiles 3nh..3nh+2 x all 32 rows
// (2 A-frags, 3 B-loads per k-step). Single-shot X staging (32x512 bf16,
// 33 KB LDS), one staging barrier, 16 k-steps. Epilogue: Qfrag (A-layout),
// Kfrag (B), Vfrag (B), Ktfrag (A-layout K^T scaled by gamma^(255-jl)).
// ---------------------------------------------------------------------------
__global__ __launch_bounds__(256, 4) void proj_kernel(
    const float* __restrict__ X, const __hip_bfloat16* __restrict__ Wfrag,
    const float* __restrict__ tabs,
    __hip_bfloat16* __restrict__ Qfrag, __hip_bfloat16* __restrict__ Kfrag,
    __hip_bfloat16* __restrict__ Vfrag, __hip_bfloat16* __restrict__ Ktfrag)
{
    __shared__ __hip_bfloat16 smem[32 * 520];  // 33280 B; main: lx[32][520]
    // epilogue reuse: bufQ=+0 [32][72], bufK=+2304 [32][72],
    //                 bufV=+4608 [64][40] (transposed)

    int tid = threadIdx.x;
    int r0 = blockIdx.x * 32;               // global row base (b*2048 + n)
    int nh = tid >> 6, lane = tid & 63, quad = lane >> 4, l15 = lane & 15;

    // ---- stage X tile 32x512 f32 -> bf16 LDS (16 float4/thread, coalesced)
#pragma unroll
    for (int u = 0; u < 16; u++) {
        int f = u * 256 + tid;
        int row = f >> 7, c = f & 127;
        float4 v = *(const float4*)(X + (r0 + row) * 512 + c * 4);
        ushort4 pk;
        pk.x = f2bf(v.x); pk.y = f2bf(v.y); pk.z = f2bf(v.z); pk.w = f2bf(v.w);
        *(ushort4*)&smem[row * 520 + c * 4] = pk;
    }
    __syncthreads();

    // acc[tl*2 + r]: tile 3nh+tl, row-half r
    floatx4 acc[6];
#pragma unroll
    for (int t = 0; t < 6; t++) acc[t] = (floatx4){0.f, 0.f, 0.f, 0.f};

#pragma unroll
    for (int ks = 0; ks < 16; ks++) {
        short8 a0 = *(const short8*)&smem[l15 * 520 + ks * 32 + quad * 8];
        short8 a1 = *(const short8*)&smem[(16 + l15) * 520 + ks * 32 + quad * 8];
#pragma unroll
        for (int tl = 0; tl < 3; tl++) {
            int tile = nh * 3 + tl;
            short8 bfr = *(const short8*)(Wfrag + ((tile * 16 + ks) * 64 + lane) * 8);
            acc[tl * 2 + 0] = __builtin_amdgcn_mfma_f32_16x16x32_bf16(a0, bfr, acc[tl * 2 + 0], 0, 0, 0);
            acc[tl * 2 + 1] = __builtin_amdgcn_mfma_f32_16x16x32_bf16(a1, bfr, acc[tl * 2 + 1], 0, 0, 0);
        }
    }
    __syncthreads();   // lx reads done before epilogue overwrites smem

    // ---- epilogue. C/D layout: col = l15, row = quad*4+rg (+16*r) ----
    __hip_bfloat16* bufQ = smem;
    __hip_bfloat16* bufK = smem + 2304;
    __hip_bfloat16* bufV = smem + 4608;
    int b = r0 >> 11, n0 = r0 & 2047;

#pragma unroll
    for (int tl = 0; tl < 3; tl++) {
        int t = nh * 3 + tl;
#pragma unroll
        for (int r = 0; r < 2; r++) {
#pragma unroll
            for (int rg = 0; rg < 4; rg++) {
                int row = r * 16 + quad * 4 + rg;    // 0..31 within block
                int n = n0 + row;
                float val = acc[tl * 2 + r][rg];
                float prt = __shfl_xor(val, 1, 64);  // lane^1 == col^1, same row
                if (t < 4) {                    // Q, xpos upscale
                    int ch = t * 16 + l15, tt = ch >> 1;
                    float co = tabs[n * 32 + tt];
                    float si = tabs[65536 + n * 32 + tt];
                    float o = (l15 & 1) ? (val * co + prt * si) : (val * co - prt * si);
                    bufQ[row * 72 + ch] = __float2bfloat16(o);
                } else if (t < 8) {             // K, xpos downscale
                    int ch = (t - 4) * 16 + l15, tt = ch >> 1;
                    float co = tabs[131072 + n * 32 + tt];
                    float si = tabs[196608 + n * 32 + tt];
                    float o = (l15 & 1) ? (val * co + prt * si) : (val * co - prt * si);
                    bufK[row * 72 + ch] = __float2bfloat16(o);
                } else {                        // V, transposed [ch][row]
                    int ch = (t - 8) * 16 + l15;
                    bufV[ch * 40 + row] = __float2bfloat16(val);
                }
            }
        }
    }
    __syncthreads();

    // ---- cooperative frag-order stores ----
    {
        int tile2 = tid >> 7, kk = (tid >> 6) & 1, ln = tid & 63;
        int q2 = ln >> 4, m15 = ln & 15;
        size_t qkbase = ((((size_t)b * 128 + (n0 >> 4) + tile2) * 2 + kk) * 64 + ln) * 8;
        uint4 vq = *(const uint4*)&bufQ[(tile2 * 16 + m15) * 72 + kk * 32 + q2 * 8];
        *(uint4*)(Qfrag + qkbase) = vq;
        uint4 vk = *(const uint4*)&bufK[(tile2 * 16 + m15) * 72 + kk * 32 + q2 * 8];
        *(uint4*)(Kfrag + qkbase) = vk;
        int t2 = tid >> 6;                  // 0..3
        uint4 vv = *(const uint4*)&bufV[(t2 * 16 + m15) * 40 + q2 * 8];
        *(uint4*)(Vfrag + ((((size_t)b * 64 + (n0 >> 5)) * 4 + t2) * 64 + ln) * 8) = vv;
    }
    // ---- Ktfrag: A-layout of K^T scaled by gamma^(255-jl), for Z = Ks^T V ----
    {
        int wdt = tid >> 6, ln2 = tid & 63;          // wdt = d-tile 0..3
        int q2 = ln2 >> 4, m15 = ln2 & 15;           // m15 = d within tile
        int jb0 = (n0 & 255) + q2 * 8;               // base key (chunk-local)
        float sc = exp2f(LOG2GAMMA * (float)(255 - jb0));
        short8 pk;
#pragma unroll
        for (int jj = 0; jj < 8; jj++) {
            float v = __bfloat162float(bufK[(q2 * 8 + jj) * 72 + wdt * 16 + m15]) * sc;
            pk[jj] = (short)f2bf(v);
            sc *= GINV;
        }
        int c = n0 >> 8, ksg = (n0 >> 5) & 7;
        *(short8*)(Ktfrag + ((((size_t)(b * 8 + c) * 4 + wdt) * 8 + ksg) * 64 + ln2) * 8) = pk;
    }
}

// ---------------------------------------------------------------------------
// Kernel 2: partial Z: Z[b][c][kh] = sum over keys kh*128..+127 of Ks^T V.
// 128 blocks = (b, c, kh), 4 waves (wave = d-tile). Output in B-frag order
// (f32) via LDS transpose; attn sums the two kh partials.
// ---------------------------------------------------------------------------
__global__ __launch_bounds__(256, 2) void zk_kernel(
    const __hip_bfloat16* __restrict__ Ktfrag,
    const __hip_bfloat16* __restrict__ Vfrag, float* __restrict__ Zf)
{
    __shared__ float zz[64 * 68];   // 17408 B

    int tid = threadIdx.x;
    int b = blockIdx.x >> 4, c = (blockIdx.x >> 1) & 7, kh = blockIdx.x & 1;
    int w = tid >> 6, lane = tid & 63, quad = lane >> 4, l15 = lane & 15;

    floatx4 acc[4];
#pragma unroll
    for (int t = 0; t < 4; t++) acc[t] = (floatx4){0.f, 0.f, 0.f, 0.f};

#pragma unroll
    for (int ks = 0; ks < 4; ks++) {
        int ksg = kh * 4 + ks;
        short8 a = *(const short8*)(Ktfrag +
            ((((size_t)(b * 8 + c) * 4 + w) * 8 + ksg) * 64 + lane) * 8);
#pragma unroll
        for (int vt = 0; vt < 4; vt++) {
            short8 bfr = *(const short8*)(Vfrag +
                ((((size_t)b * 64 + c * 8 + ksg) * 4 + vt) * 64 + lane) * 8);
            acc[vt] = __builtin_amdgcn_mfma_f32_16x16x32_bf16(a, bfr, acc[vt], 0, 0, 0);
        }
    }
    // C-layout (row d = w*16+quad*4+rg, col v = vt*16+l15) -> LDS
#pragma unroll
    for (int vt = 0; vt < 4; vt++)
#pragma unroll
        for (int rg = 0; rg < 4; rg++)
            zz[(w * 16 + quad * 4 + rg) * 68 + vt * 16 + l15] = acc[vt][rg];
    __syncthreads();

    // B-frag-order f32 store: thread = (vt, lane); 2 kk x 8 jd values
    {
        int vt = tid >> 6;
#pragma unroll
        for (int kk = 0; kk < 2; kk++) {
            float v[8];
#pragma unroll
            for (int jd = 0; jd < 8; jd++)
                v[jd] = zz[(kk * 32 + quad * 8 + jd) * 68 + vt * 16 + l15];
            float* zp = Zf +
                ((((((size_t)(b * 8 + c) * 2 + kh) * 4 + vt) * 2 + kk) * 64 + lane) * 8);
            *(float4*)zp       = (float4){v[0], v[1], v[2], v[3]};
            *(float4*)(zp + 4) = (float4){v[4], v[5], v[6], v[7]};
        }
    }
}

// ---------------------------------------------------------------------------
// Kernel 3: per-q-tile retention. 1024 blocks = (b, 128 q-tiles), 128 thr
// (2 waves). Wave h: diagonal-chunk keys h*128..+127 (QK + |i-j| decay + P
// round-trip + PV) and the kk=h half of the cross term Q @ H with post-MFMA
// row scaling by gamma^(il+1); H = sum_m g^(256m) * (Z[qc-1-m][0]+Z[..][1]).
// One barrier total.
// ---------------------------------------------------------------------------
__global__ __launch_bounds__(128, 4) void attn_kernel(
    const __hip_bfloat16* __restrict__ Qfrag, const __hip_bfloat16* __restrict__ Kfrag,
    const __hip_bfloat16* __restrict__ Vfrag, const float* __restrict__ Zf,
    float* __restrict__ out)
{
    __shared__ __hip_bfloat16 P[2 * 16 * 132];   // 8448 B (stride 132)
    __shared__ float obuf[16 * 68];              // 4352 B

    int tid = threadIdx.x;
    int b = blockIdx.x >> 7, qt = blockIdx.x & 127;
    int qc = qt >> 4;
    int h = tid >> 6, lane = tid & 63, quad = lane >> 4, l15 = lane & 15;
    __hip_bfloat16* Pw = P + h * 2112;

    short8 qf[2];
#pragma unroll
    for (int kk = 0; kk < 2; kk++)
        qf[kk] = *(const short8*)(Qfrag + (((size_t)(b * 128 + qt) * 2 + kk) * 64 + lane) * 8);

    floatx4 o[4];
#pragma unroll
    for (int t = 0; t < 4; t++) o[t] = (floatx4){0.f, 0.f, 0.f, 0.f};

    int il0 = (qt & 15) * 16 + quad * 4;         // chunk-local q row base

    // ---- diagonal chunk, this wave's 128 keys, 2 groups of 4 ktiles ----
#pragma unroll
    for (int g = 0; g < 2; g++) {
        floatx4 s[4];
#pragma unroll
        for (int t = 0; t < 4; t++) s[t] = (floatx4){0.f, 0.f, 0.f, 0.f};
#pragma unroll
        for (int t = 0; t < 4; t++) {
            int kt = qc * 16 + h * 8 + g * 4 + t;
#pragma unroll
            for (int kk = 0; kk < 2; kk++) {
                short8 bfr = *(const short8*)(Kfrag +
                    (((size_t)(b * 128 + kt) * 2 + kk) * 64 + lane) * 8);
                s[t] = __builtin_amdgcn_mfma_f32_16x16x32_bf16(qf[kk], bfr, s[t], 0, 0, 0);
            }
        }
#pragma unroll
        for (int t = 0; t < 4; t++) {
            int jl = h * 128 + (g * 4 + t) * 16 + l15;
#pragma unroll
            for (int rg = 0; rg < 4; rg++) {
                int d = il0 + rg - jl; d = (d < 0) ? -d : d;
                float p = s[t][rg] * exp2f(LOG2GAMMA * (float)d);
                Pw[(quad * 4 + rg) * 132 + (g * 4 + t) * 16 + l15] = __float2bfloat16(p);
            }
        }
    }
    // PV over this wave's 128 keys (in-wave DS ordering, no barrier)
#pragma unroll
    for (int ks = 0; ks < 4; ks++) {
        short8 a = *(const short8*)&Pw[l15 * 132 + ks * 32 + quad * 8];
#pragma unroll
        for (int vt = 0; vt < 4; vt++) {
            short8 bfr = *(const short8*)(Vfrag +
                ((((size_t)b * 64 + qc * 8 + h * 4 + ks) * 4 + vt) * 64 + lane) * 8);
            o[vt] = __builtin_amdgcn_mfma_f32_16x16x32_bf16(a, bfr, o[vt], 0, 0, 0);
        }
    }

    // ---- cross-chunk term: Q @ H into oc, post-scale by gamma^(il+1) ----
    if (qc > 0) {
        floatx4 oc[4];
#pragma unroll
        for (int t = 0; t < 4; t++) oc[t] = (floatx4){0.f, 0.f, 0.f, 0.f};
        int nz = (qc < 3) ? qc : 3;
        float cm1 = exp2f(LOG2GAMMA * 256.0f);
        float cm2 = exp2f(LOG2GAMMA * 512.0f);
#pragma unroll
        for (int vt = 0; vt < 4; vt++) {
            float hv[8];
#pragma unroll
            for (int jd = 0; jd < 8; jd++) hv[jd] = 0.f;
            for (int m = 0; m < nz; m++) {
                float cm = (m == 0) ? 1.0f : ((m == 1) ? cm1 : cm2);
#pragma unroll
                for (int kh = 0; kh < 2; kh++) {
                    const float* zp = Zf +
                        ((((((size_t)(b * 8 + qc - 1 - m) * 2 + kh) * 4 + vt) * 2 + h) * 64 + lane) * 8);
                    float4 z0 = *(const float4*)zp;
                    float4 z1 = *(const float4*)(zp + 4);
                    hv[0] += cm * z0.x; hv[1] += cm * z0.y;
                    hv[2] += cm * z0.z; hv[3] += cm * z0.w;
                    hv[4] += cm * z1.x; hv[5] += cm * z1.y;
                    hv[6] += cm * z1.z; hv[7] += cm * z1.w;
                }
            }
            short8 hb;
#pragma unroll
            for (int jd = 0; jd < 8; jd++) hb[jd] = (short)f2bf(hv[jd]);
            oc[vt] = __builtin_amdgcn_mfma_f32_16x16x32_bf16(qf[h], hb, oc[vt], 0, 0, 0);
        }
        float rs[4];
#pragma unroll
        for (int rg = 0; rg < 4; rg++)
            rs[rg] = exp2f(LOG2GAMMA * (float)(il0 + rg + 1));
#pragma unroll
        for (int vt = 0; vt < 4; vt++)
#pragma unroll
            for (int rg = 0; rg < 4; rg++)
                o[vt][rg] += oc[vt][rg] * rs[rg];
    }

    // ---- combine the two waves ----
    if (h == 1) {
#pragma unroll
        for (int vt = 0; vt < 4; vt++)
#pragma unroll
            for (int rg = 0; rg < 4; rg++)
                obuf[(quad * 4 + rg) * 68 + vt * 16 + l15] = o[vt][rg];
    }
    __syncthreads();
    if (h == 0) {
        int rbase = b * 2048 + qt * 16 + quad * 4;
#pragma unroll
        for (int vt = 0; vt < 4; vt++)
#pragma unroll
            for (int rg = 0; rg < 4; rg++)
                out[(size_t)(rbase + rg) * 64 + vt * 16 + l15] =
                    o[vt][rg] + obuf[(quad * 4 + rg) * 68 + vt * 16 + l15];
    }
}

// ---------------------------------------------------------------------------
extern "C" void kernel_launch(void* const* d_in, const int* in_sizes, int n_in,
                              void* d_out, int out_size, void* d_ws, size_t ws_size,
                              hipStream_t stream) {
    const float* X  = (const float*)d_in[0];
    const float* Wq = (const float*)d_in[1];
    const float* Wk = (const float*)d_in[2];
    const float* Wv = (const float*)d_in[3];
    float* out = (float*)d_out;

    char* ws = (char*)d_ws;
    __hip_bfloat16* Wfrag  = (__hip_bfloat16*)(ws);             // 196608 B
    float*          tabs   = (float*)(ws + 196608);             // 1048576 B
    __hip_bfloat16* Qfrag  = (__hip_bfloat16*)(ws + 1245184);   // 2097152 B
    __hip_bfloat16* Kfrag  = (__hip_bfloat16*)(ws + 3342336);   // 2097152 B
    __hip_bfloat16* Vfrag  = (__hip_bfloat16*)(ws + 5439488);   // 2097152 B
    __hip_bfloat16* Ktfrag = (__hip_bfloat16*)(ws + 7536640);   // 2097152 B
    float*          Zf     = (float*)(ws + 9633792);            // 2097152 B

    prep_kernel<<<1408, 256, 0, stream>>>(Wq, Wk, Wv, Wfrag, tabs);
    proj_kernel<<<512, 256, 0, stream>>>(X, Wfrag, tabs, Qfrag, Kfrag, Vfrag, Ktfrag);
    zk_kernel<<<128, 256, 0, stream>>>(Ktfrag, Vfrag, Zf);
    attn_kernel<<<1024, 128, 0, stream>>>(Qfrag, Kfrag, Vfrag, Zf, out);
}